// Round 7
// baseline (157.493 us; speedup 1.0000x reference)
//
#include <hip/hip_runtime.h>

#define BATCH 512
#define SEQ   512
#define VOCAB 1000
#define EMB   100
#define UNITS 64
#define WPB   8                      // 8 waves/block -> 2 waves per SIMD (SMT)
#define SC    2.88539008177792681f   // 2*log2(e): v_exp_f32(SC*s) == e^{2s}

typedef float v2f __attribute__((ext_vector_type(2)));

// ---------------------------------------------------------------------------
// Kernel 1: P[v][u] = SC*( (emb[v]@Wxh)[u] + b[u] + colsum(Whh)[u] )
// colsum fold supports the r-recurrence: y = x + W.h, h = 1-2r
//   =>  y = (x + W.1) - 2*W.r  -- the per-step h=fma(-2,r,1) vanishes.
// ---------------------------------------------------------------------------
__global__ __launch_bounds__(64) void proj_kernel(
    const float* __restrict__ emb, const float* __restrict__ Wxh,
    const float* __restrict__ bias, const float* __restrict__ Whh,
    float* __restrict__ P) {
  const int v = blockIdx.x;
  const int u = threadIdx.x;
  const float* e = emb + v * EMB;
  float acc = bias[u];
#pragma unroll 5
  for (int d = 0; d < EMB; ++d) acc += e[d] * Wxh[d * UNITS + u];
  float csum = 0.f;
#pragma unroll 8
  for (int i = 0; i < UNITS; ++i) csum += Whh[i * UNITS + u];
  P[v * UNITS + u] = SC * (acc + csum);
}

// ---------------------------------------------------------------------------
// DPP all-gather of one value/lane across the lane's own 16-lane row.
// Slot->source-lane permutation calibrated at runtime on lane_id.
// ---------------------------------------------------------------------------
#define DPP_I(src, ctrl) __builtin_amdgcn_update_dpp(0, (src), (ctrl), 0xF, 0xF, true)

#define GATHER_ROW(v_, g_)                                          \
  do {                                                              \
    g_[0] = DPP_I((v_), 0x00);  /* quad_perm:[0,0,0,0] */           \
    g_[1] = DPP_I((v_), 0x55);  /* quad_perm:[1,1,1,1] */           \
    g_[2] = DPP_I((v_), 0xAA);  /* quad_perm:[2,2,2,2] */           \
    g_[3] = DPP_I((v_), 0xFF);  /* quad_perm:[3,3,3,3] */           \
    g_[4]  = DPP_I(g_[0], 0x124); g_[5]  = DPP_I(g_[1], 0x124);     \
    g_[6]  = DPP_I(g_[2], 0x124); g_[7]  = DPP_I(g_[3], 0x124);     \
    g_[8]  = DPP_I(g_[0], 0x128); g_[9]  = DPP_I(g_[1], 0x128);     \
    g_[10] = DPP_I(g_[2], 0x128); g_[11] = DPP_I(g_[3], 0x128);     \
    g_[12] = DPP_I(g_[0], 0x12C); g_[13] = DPP_I(g_[1], 0x12C);     \
    g_[14] = DPP_I(g_[2], 0x12C); g_[15] = DPP_I(g_[3], 0x12C);     \
  } while (0)

// lane^16 / lane^32 exchange (r4-proven form: duplicate, swap, cndmask-select).
__device__ __forceinline__ float sw16(float v, bool sel) {
  int x = __float_as_int(v), y = x;
  asm volatile("s_nop 1\n\tv_permlane16_swap_b32 %0, %1" : "+v"(x), "+v"(y));
  return sel ? __int_as_float(x) : __int_as_float(y);
}
__device__ __forceinline__ float sw32(float v, bool sel) {
  int x = __float_as_int(v), y = x;
  asm volatile("s_nop 1\n\tv_permlane32_swap_b32 %0, %1" : "+v"(x), "+v"(y));
  return sel ? __int_as_float(x) : __int_as_float(y);
}

// ---------------------------------------------------------------------------
// Kernel 2: sequential scan on r(t) = 1/(e^{2s}+1). ONE row per wave, math
// identical to r6 (99.5us, 470 cyc/step, VALUBusy 31% -> ~320 cyc/step of
// in-order stall). Single variable this round: EIGHT waves per block so each
// SIMD hosts TWO independent waves -- hardware SMT fills one wave's
// dependency bubbles with the other wave's ready instructions.
// VGPR provisioning: no launch_bounds second arg (r3's "2" was read as
// 2 blocks/CU -> cap 128 < 132 -> collapse to 56 VGPR + scratch);
// waves_per_eu(2) -> cap 256 > 132 needed.
// ---------------------------------------------------------------------------
__global__ __launch_bounds__(64 * WPB)
__attribute__((amdgpu_waves_per_eu(2)))
void scan_kernel(
    const int* __restrict__ tok, const float* __restrict__ P,
    const float* __restrict__ Whh, const float* __restrict__ Wout,
    const float* __restrict__ bout, float* __restrict__ out) {
  const int lane = threadIdx.x & 63;
  const int row  = blockIdx.x * WPB + (threadIdx.x >> 6);

  // ---- calibration: gather permutation + swap register-select ----
  int gcal[16];
  GATHER_ROW(lane, gcal);  // gcal[s] = source lane (== unit index) of slot s

  int x16 = lane, y16 = lane;
  asm volatile("s_nop 1\n\tv_permlane16_swap_b32 %0, %1" : "+v"(x16), "+v"(y16));
  const bool sel16 = (x16 == (lane ^ 16));
  int x32 = lane, y32 = lane;
  asm volatile("s_nop 1\n\tv_permlane32_swap_b32 %0, %1" : "+v"(x32), "+v"(y32));
  const bool sel32 = (x32 == (lane ^ 32));

  // ---- weights: 4 columns (lane, ^16, ^32, ^48) x own-row 16 inputs,
  // permuted to gather order, scaled by -2*SC (r-recurrence), pinned ----
  const int c0 = lane, c1 = lane ^ 16, c2 = lane ^ 32, c3 = lane ^ 48;
  v2f w0[8], w1[8], w2[8], w3[8];
#pragma unroll
  for (int s = 0; s < 8; ++s) {
    const int i0 = gcal[2 * s] * UNITS, i1 = gcal[2 * s + 1] * UNITS;
    float t00 = -2.f * SC * Whh[i0 + c0], t01 = -2.f * SC * Whh[i1 + c0];
    float t10 = -2.f * SC * Whh[i0 + c1], t11 = -2.f * SC * Whh[i1 + c1];
    float t20 = -2.f * SC * Whh[i0 + c2], t21 = -2.f * SC * Whh[i1 + c2];
    float t30 = -2.f * SC * Whh[i0 + c3], t31 = -2.f * SC * Whh[i1 + c3];
    asm volatile("" : "+v"(t00), "+v"(t01), "+v"(t10), "+v"(t11));
    asm volatile("" : "+v"(t20), "+v"(t21), "+v"(t30), "+v"(t31));
    w0[s].x = t00; w0[s].y = t01;  w1[s].x = t10; w1[s].y = t11;
    w2[s].x = t20; w2[s].y = t21;  w3[s].x = t30; w3[s].y = t31;
  }

  // ---- all 512 tokens of this row, pre-scaled by UNITS (coalesced) ----
  int tokv[SEQ / 64];
  const int* trow = tok + (long)row * SEQ;
#pragma unroll
  for (int c = 0; c < SEQ / 64; ++c) {
    int t = trow[c * 64 + lane] * UNITS;
    asm volatile("" : "+v"(t));
    tokv[c] = t;
  }

  float r = 0.5f;  // h = 0  <=>  r = (1-h)/2 = 0.5

  // distance-2 P prefetch ring.
  float a0 = P[(long)__builtin_amdgcn_readlane(tokv[0], 0) + lane];
  float a1 = P[(long)__builtin_amdgcn_readlane(tokv[0], 1) + lane];

#pragma unroll
  for (int c = 0; c < SEQ / 64; ++c) {
#pragma unroll
    for (int tt = 0; tt < 64; ++tt) {  // full unroll: readlane lanes become
      float a_cur = a0;                // immediates, ring movs rename away
      a0 = a1;
      int tkn = __builtin_amdgcn_readlane(tokv[c], (tt + 2) & 63);
      a1 = P[(long)tkn + lane];  // wrong row at tt=62,63; patched below

      // ---- in-register all-gather of r across own 16-lane row ----
      int gi[16];
      GATHER_ROW(__float_as_int(r), gi);

      // ---- 4 column partials, 8-deep pk_fma chains; P' folded into
      // acc0 init; -2*SC folded into weights ----
      v2f acc0, acc1 = {0.f, 0.f}, acc2 = {0.f, 0.f}, acc3 = {0.f, 0.f};
      acc0.x = a_cur; acc0.y = 0.f;
#pragma unroll
      for (int s = 0; s < 8; ++s) {
        v2f gp;
        gp.x = __int_as_float(gi[2 * s]);
        gp.y = __int_as_float(gi[2 * s + 1]);
        acc0 += gp * w0[s];
        acc1 += gp * w1[s];
        acc2 += gp * w2[s];
        acc3 += gp * w3[s];
      }
      float p0 = acc0.x + acc0.y;   // col lane      (incl. a_cur)
      float p1 = acc1.x + acc1.y;   // col lane^16
      float p2 = acc2.x + acc2.y;   // col lane^32
      float p3 = acc3.x + acc3.y;   // col lane^48

      // combine: yv[j] = P0(j) + P1(j^16) + P2(j^32) + P3(j^48) = SC * s(t+1)
      float s1 = p0 + sw16(p1, sel16);
      float s2 = p2 + sw16(p3, sel16);
      float yv = s1 + sw32(s2, sel32);

      // r = 1/(e^{2s}+1);  e^{2s} = 2^yv. Trans ops are HW-interlocked.
      float ex; asm("v_exp_f32 %0, %1" : "=v"(ex) : "v"(yv));
      r = __builtin_amdgcn_rcpf(ex + 1.f);
    }
    if (c + 1 < SEQ / 64) {  // restore ring invariant for next chunk
      a0 = P[(long)__builtin_amdgcn_readlane(tokv[c + 1], 0) + lane];
      a1 = P[(long)__builtin_amdgcn_readlane(tokv[c + 1], 1) + lane];
    }
  }

  // h = 1 - 2r (once); out[row] = sigmoid(sum_j h[j]*Wout[j] + bout)
  float h = __builtin_fmaf(-2.f, r, 1.f);
  float p = h * Wout[lane];
#pragma unroll
  for (int off = 32; off > 0; off >>= 1) p += __shfl_xor(p, off);
  if (lane == 0) out[row] = 1.f / (1.f + __expf(-(p + bout[0])));
}

extern "C" void kernel_launch(void* const* d_in, const int* in_sizes, int n_in,
                              void* d_out, int out_size, void* d_ws, size_t ws_size,
                              hipStream_t stream) {
  const int*   tok  = (const int*)  d_in[0];  // [BATCH, SEQ] int32
  const float* emb  = (const float*)d_in[1];  // [VOCAB, EMB]
  const float* Wxh  = (const float*)d_in[2];  // [EMB, UNITS]
  const float* Whh  = (const float*)d_in[3];  // [UNITS, UNITS]
  const float* bias = (const float*)d_in[4];  // [UNITS]
  const float* Wout = (const float*)d_in[5];  // [UNITS, 1]
  const float* bout = (const float*)d_in[6];  // [1]
  float* out = (float*)d_out;                 // [BATCH, 1] fp32

  float* P = (float*)d_ws;                    // VOCAB*UNITS fp32 = 256 KB

  proj_kernel<<<VOCAB, 64, 0, stream>>>(emb, Wxh, bias, Whh, P);
  scan_kernel<<<BATCH / WPB, 64 * WPB, 0, stream>>>(tok, P, Whh, Wout, bout, out);
}